// Round 1
// baseline (1650.394 us; speedup 1.0000x reference)
//
#include <hip/hip_runtime.h>

#define HW 128
#define NB 32
#define NL 68
#define NC 16

__device__ __forceinline__ int gate_of(int l) {
    // eye=0 (17:27 & 36:48), nose=1 (27:36), jaw=2 (0:17), mouth=3 (48:68)
    return (l < 17) ? 2 : (l < 27) ? 0 : (l < 36) ? 1 : (l < 48) ? 0 : 3;
}

// Reorder w_fea [g][l][o][ci][tap] -> w2 [g][l][ci][o][tap] (contiguous 144 per ci)
__global__ __launch_bounds__(256) void reorder_w_kernel(const float* __restrict__ w,
                                                        float* __restrict__ w2) {
    int i = blockIdx.x * 256 + threadIdx.x;
    if (i >= 4 * 3 * 16 * 16 * 9) return;
    int tap = i % 9;
    int ci  = (i / 9) % 16;
    int o   = (i / 144) % 16;
    int l   = (i / 2304) % 3;
    int g   = i / 6912;
    w2[((((g * 3 + l) * 16 + ci) * 16 + o) * 9) + tap] = w[i];
}

// Stage A: 68 depthwise towers of 5 3x3 convs, group-summed into gates[b][4][H][W]
__global__ __launch_bounds__(256) void lm_towers_kernel(
    const float* __restrict__ lm, const float* __restrict__ wlm,
    const float* __restrict__ blm, float* __restrict__ gates)
{
    __shared__ float bufA[42 * 42];
    __shared__ float bufB[42 * 42];
    __shared__ float gacc[4 * 1024];

    const int tid  = threadIdx.x;
    const int b    = blockIdx.x >> 4;
    const int tile = blockIdx.x & 15;
    const int oy   = (tile >> 2) << 5;
    const int ox   = (tile & 3) << 5;

    for (int i = tid; i < 4096; i += 256) gacc[i] = 0.f;  // slot owned by one thread

    for (int l = 0; l < NL; ++l) {
        const float* src = lm + (size_t)(b * NL + l) * (HW * HW);
        for (int i = tid; i < 42 * 42; i += 256) {
            int r = i / 42, c = i - r * 42;
            int gy = oy - 5 + r, gx = ox - 5 + c;
            float v = 0.f;
            if ((unsigned)gy < (unsigned)HW && (unsigned)gx < (unsigned)HW)
                v = src[gy * HW + gx];
            bufA[i] = v;
        }
        __syncthreads();

        float* pin = bufA;
        float* pout = bufB;
        #pragma unroll
        for (int k = 0; k < 5; ++k) {
            const float* wp = wlm + (k * NL + l) * 9;
            float w0 = wp[0], w1 = wp[1], w2v = wp[2],
                  w3 = wp[3], w4 = wp[4], w5v = wp[5],
                  w6 = wp[6], w7 = wp[7], w8v = wp[8];
            float bias = blm[k * NL + l];
            const int lo = k + 1;
            const int HT = (40 - 2 * k) >> 1;   // micro-tiles per side (2x2 px each)
            for (int m = tid; m < HT * HT; m += 256) {
                int mr = m / HT, mc = m - mr * HT;
                int r = lo + 2 * mr, c0 = lo + 2 * mc;
                float x[4][4];
                #pragma unroll
                for (int dr = 0; dr < 4; ++dr)
                    #pragma unroll
                    for (int dc = 0; dc < 4; ++dc)
                        x[dr][dc] = pin[(r - 1 + dr) * 42 + (c0 - 1 + dc)];
                #pragma unroll
                for (int i2 = 0; i2 < 2; ++i2) {
                    #pragma unroll
                    for (int j2 = 0; j2 < 2; ++j2) {
                        float s = bias
                          + w0 * x[i2][j2]     + w1 * x[i2][j2 + 1]     + w2v * x[i2][j2 + 2]
                          + w3 * x[i2 + 1][j2] + w4 * x[i2 + 1][j2 + 1] + w5v * x[i2 + 1][j2 + 2]
                          + w6 * x[i2 + 2][j2] + w7 * x[i2 + 2][j2 + 1] + w8v * x[i2 + 2][j2 + 2];
                        int gy = oy - 5 + r + i2, gx = ox - 5 + c0 + j2;
                        bool in = (unsigned)gy < (unsigned)HW && (unsigned)gx < (unsigned)HW;
                        // outside-image intermediates must be 0 (next layer's zero padding)
                        pout[(r + i2) * 42 + (c0 + j2)] = in ? s : 0.f;
                    }
                }
            }
            __syncthreads();
            float* t = pin; pin = pout; pout = t;
        }
        // pin = layer-5 output, valid on [5,37)^2
        const int g = gate_of(l);
        for (int i = tid; i < 1024; i += 256) {
            int r = i >> 5, c = i & 31;
            gacc[g * 1024 + i] += pin[(5 + r) * 42 + (5 + c)];
        }
        // no barrier needed: next iter only writes bufA before its barrier
    }
    for (int i = tid; i < 4096; i += 256) {
        int g = i >> 10, p = i & 1023;
        int r = p >> 5, c = p & 31;
        gates[((size_t)(b * 4 + g) * HW + (oy + r)) * HW + (ox + c)] = gacc[i];
    }
}

// Stage B: 4 branches x 3 dense 16->16 3x3 convs, gated accumulate into out
__global__ __launch_bounds__(256) void fea_kernel(
    const float* __restrict__ fea, const float* __restrict__ w2,
    const float* __restrict__ bfe, const float* __restrict__ gates,
    float* __restrict__ out)
{
    __shared__ float fA[16 * 484];   // 22x22 per channel
    __shared__ float fB[16 * 400];   // 20x20 per channel

    const int tid  = threadIdx.x;
    const int b    = blockIdx.x >> 6;
    const int tile = blockIdx.x & 63;
    const int oy   = (tile >> 3) << 4;
    const int ox   = (tile & 7) << 4;
    const int pr   = tid >> 4, pc = tid & 15;   // this thread's output pixel

    float oacc[16];
    #pragma unroll
    for (int o = 0; o < 16; ++o) oacc[o] = 0.f;

    float gte[4];
    #pragma unroll
    for (int g = 0; g < 4; ++g)
        gte[g] = gates[((size_t)(b * 4 + g) * HW + (oy + pr)) * HW + (ox + pc)];

    for (int g = 0; g < 4; ++g) {
        // stage features tile with halo 3
        for (int i = tid; i < 16 * 484; i += 256) {
            int ch = i / 484, p = i - ch * 484;
            int rr = p / 22, cc = p - rr * 22;
            int gy = oy - 3 + rr, gx = ox - 3 + cc;
            float v = 0.f;
            if ((unsigned)gy < (unsigned)HW && (unsigned)gx < (unsigned)HW)
                v = fea[((size_t)(b * 16 + ch) * HW + gy) * HW + gx];
            fA[i] = v;
        }
        __syncthreads();

        // layer 0: fA(22x22) -> fB(20x20)
        {
            const float* wl = w2 + (g * 3 + 0) * 2304;
            const float* bl = bfe + (g * 3 + 0) * 16;
            for (int m = tid; m < 400; m += 256) {
                int r = m / 20, c = m - r * 20;
                float acc[16];
                #pragma unroll
                for (int o = 0; o < 16; ++o) acc[o] = bl[o];
                for (int ci = 0; ci < 16; ++ci) {
                    float v[9];
                    #pragma unroll
                    for (int dr = 0; dr < 3; ++dr)
                        #pragma unroll
                        for (int dc = 0; dc < 3; ++dc)
                            v[dr * 3 + dc] = fA[ci * 484 + (r + dr) * 22 + (c + dc)];
                    const float* wp = wl + ci * 144;
                    #pragma unroll
                    for (int o = 0; o < 16; ++o)
                        #pragma unroll
                        for (int t9 = 0; t9 < 9; ++t9)
                            acc[o] += wp[o * 9 + t9] * v[t9];
                }
                int gy = oy + r - 2, gx = ox + c - 2;
                bool in = (unsigned)gy < (unsigned)HW && (unsigned)gx < (unsigned)HW;
                #pragma unroll
                for (int o = 0; o < 16; ++o)
                    fB[o * 400 + m] = in ? acc[o] : 0.f;
            }
        }
        __syncthreads();

        // layer 1: fB(20x20) -> fA at offset (2,2), 18x18
        {
            const float* wl = w2 + (g * 3 + 1) * 2304;
            const float* bl = bfe + (g * 3 + 1) * 16;
            for (int m = tid; m < 324; m += 256) {
                int r = m / 18, c = m - r * 18;
                float acc[16];
                #pragma unroll
                for (int o = 0; o < 16; ++o) acc[o] = bl[o];
                for (int ci = 0; ci < 16; ++ci) {
                    float v[9];
                    #pragma unroll
                    for (int dr = 0; dr < 3; ++dr)
                        #pragma unroll
                        for (int dc = 0; dc < 3; ++dc)
                            v[dr * 3 + dc] = fB[ci * 400 + (r + dr) * 20 + (c + dc)];
                    const float* wp = wl + ci * 144;
                    #pragma unroll
                    for (int o = 0; o < 16; ++o)
                        #pragma unroll
                        for (int t9 = 0; t9 < 9; ++t9)
                            acc[o] += wp[o * 9 + t9] * v[t9];
                }
                int gy = oy + r - 1, gx = ox + c - 1;
                bool in = (unsigned)gy < (unsigned)HW && (unsigned)gx < (unsigned)HW;
                #pragma unroll
                for (int o = 0; o < 16; ++o)
                    fA[o * 484 + (r + 2) * 22 + (c + 2)] = in ? acc[o] : 0.f;
            }
        }
        __syncthreads();

        // layer 2: fA offset(2,2) 18x18 -> this thread's output pixel, fused gate
        {
            const float* wl = w2 + (g * 3 + 2) * 2304;
            const float* bl = bfe + (g * 3 + 2) * 16;
            float acc[16];
            #pragma unroll
            for (int o = 0; o < 16; ++o) acc[o] = bl[o];
            for (int ci = 0; ci < 16; ++ci) {
                float v[9];
                #pragma unroll
                for (int dr = 0; dr < 3; ++dr)
                    #pragma unroll
                    for (int dc = 0; dc < 3; ++dc)
                        v[dr * 3 + dc] = fA[ci * 484 + (pr + 2 + dr) * 22 + (pc + 2 + dc)];
                const float* wp = wl + ci * 144;
                #pragma unroll
                for (int o = 0; o < 16; ++o)
                    #pragma unroll
                    for (int t9 = 0; t9 < 9; ++t9)
                        acc[o] += wp[o * 9 + t9] * v[t9];
            }
            #pragma unroll
            for (int o = 0; o < 16; ++o) oacc[o] += acc[o] * gte[g];
        }
        __syncthreads();  // protect fA before next branch's staging
    }

    #pragma unroll
    for (int o = 0; o < 16; ++o)
        out[((size_t)(b * 16 + o) * HW + (oy + pr)) * HW + (ox + pc)] = oacc[o];
}

extern "C" void kernel_launch(void* const* d_in, const int* in_sizes, int n_in,
                              void* d_out, int out_size, void* d_ws, size_t ws_size,
                              hipStream_t stream) {
    const float* lm  = (const float*)d_in[0];
    const float* fea = (const float*)d_in[1];
    const float* wlm = (const float*)d_in[2];
    const float* blm = (const float*)d_in[3];
    const float* wfe = (const float*)d_in[4];
    const float* bfe = (const float*)d_in[5];
    float* out = (float*)d_out;

    float* gates = (float*)d_ws;                       // 32*4*128*128 floats = 8 MB
    float* w2    = gates + (size_t)NB * 4 * HW * HW;   // 27648 floats

    reorder_w_kernel<<<108, 256, 0, stream>>>(wfe, w2);
    lm_towers_kernel<<<NB * 16, 256, 0, stream>>>(lm, wlm, blm, gates);
    fea_kernel<<<NB * 64, 256, 0, stream>>>(fea, w2, bfe, gates, out);
}

// Round 2
// 539.904 us; speedup vs baseline: 3.0568x; 3.0568x over previous
//
#include <hip/hip_runtime.h>

#define HW 128
#define NB 32
#define NL 68
#define NC 16

typedef __attribute__((ext_vector_type(8))) short bf8;
typedef __attribute__((ext_vector_type(8))) unsigned short us8;
typedef __attribute__((ext_vector_type(4))) unsigned short us4;
typedef __attribute__((ext_vector_type(4))) float f4;

__device__ __forceinline__ unsigned short f2bf(float f) {
    unsigned int u = __float_as_uint(f);
    u += 0x7fffu + ((u >> 16) & 1u);   // RNE
    return (unsigned short)(u >> 16);
}

__device__ __forceinline__ int gate_of(int l) {
    return (l < 17) ? 2 : (l < 27) ? 0 : (l < 36) ? 1 : (l < 48) ? 0 : 3;
}

// Wa[gl][o][k]: k = m*32 + kl, kl = tp*16 + ci (tp=tap&1 within pair), tap = 2m+tp
__global__ __launch_bounds__(256) void reorder_wa_kernel(const float* __restrict__ w,
                                                         unsigned short* __restrict__ wa) {
    int i = blockIdx.x * 256 + threadIdx.x;
    if (i >= 12 * 16 * 160) return;
    int k  = i % 160;
    int o  = (i / 160) % 16;
    int gl = i / 2560;
    int kl = k & 31, m = k >> 5;
    int tap = 2 * m + (kl >> 4);
    int ci  = kl & 15;
    float v = (tap < 9) ? w[((gl * 16 + o) * 16 + ci) * 9 + tap] : 0.f;
    wa[i] = f2bf(v);
}

// Stage A (unchanged): 68 depthwise towers of 5 3x3 convs -> gates[b][4][H][W]
__global__ __launch_bounds__(256) void lm_towers_kernel(
    const float* __restrict__ lm, const float* __restrict__ wlm,
    const float* __restrict__ blm, float* __restrict__ gates)
{
    __shared__ float bufA[42 * 42];
    __shared__ float bufB[42 * 42];
    __shared__ float gacc[4 * 1024];

    const int tid  = threadIdx.x;
    const int b    = blockIdx.x >> 4;
    const int tile = blockIdx.x & 15;
    const int oy   = (tile >> 2) << 5;
    const int ox   = (tile & 3) << 5;

    for (int i = tid; i < 4096; i += 256) gacc[i] = 0.f;

    for (int l = 0; l < NL; ++l) {
        const float* src = lm + (size_t)(b * NL + l) * (HW * HW);
        for (int i = tid; i < 42 * 42; i += 256) {
            int r = i / 42, c = i - r * 42;
            int gy = oy - 5 + r, gx = ox - 5 + c;
            float v = 0.f;
            if ((unsigned)gy < (unsigned)HW && (unsigned)gx < (unsigned)HW)
                v = src[gy * HW + gx];
            bufA[i] = v;
        }
        __syncthreads();

        float* pin = bufA;
        float* pout = bufB;
        #pragma unroll
        for (int k = 0; k < 5; ++k) {
            const float* wp = wlm + (k * NL + l) * 9;
            float w0 = wp[0], w1 = wp[1], w2v = wp[2],
                  w3 = wp[3], w4 = wp[4], w5v = wp[5],
                  w6 = wp[6], w7 = wp[7], w8v = wp[8];
            float bias = blm[k * NL + l];
            const int lo = k + 1;
            const int HT = (40 - 2 * k) >> 1;
            for (int m = tid; m < HT * HT; m += 256) {
                int mr = m / HT, mc = m - mr * HT;
                int r = lo + 2 * mr, c0 = lo + 2 * mc;
                float x[4][4];
                #pragma unroll
                for (int dr = 0; dr < 4; ++dr)
                    #pragma unroll
                    for (int dc = 0; dc < 4; ++dc)
                        x[dr][dc] = pin[(r - 1 + dr) * 42 + (c0 - 1 + dc)];
                #pragma unroll
                for (int i2 = 0; i2 < 2; ++i2) {
                    #pragma unroll
                    for (int j2 = 0; j2 < 2; ++j2) {
                        float s = bias
                          + w0 * x[i2][j2]     + w1 * x[i2][j2 + 1]     + w2v * x[i2][j2 + 2]
                          + w3 * x[i2 + 1][j2] + w4 * x[i2 + 1][j2 + 1] + w5v * x[i2 + 1][j2 + 2]
                          + w6 * x[i2 + 2][j2] + w7 * x[i2 + 2][j2 + 1] + w8v * x[i2 + 2][j2 + 2];
                        int gy = oy - 5 + r + i2, gx = ox - 5 + c0 + j2;
                        bool in = (unsigned)gy < (unsigned)HW && (unsigned)gx < (unsigned)HW;
                        pout[(r + i2) * 42 + (c0 + j2)] = in ? s : 0.f;
                    }
                }
            }
            __syncthreads();
            float* t = pin; pin = pout; pout = t;
        }
        const int g = gate_of(l);
        for (int i = tid; i < 1024; i += 256) {
            int r = i >> 5, c = i & 31;
            gacc[g * 1024 + i] += pin[(5 + r) * 42 + (5 + c)];
        }
    }
    for (int i = tid; i < 4096; i += 256) {
        int g = i >> 10, p = i & 1023;
        int r = p >> 5, c = p & 31;
        gates[((size_t)(b * 4 + g) * HW + (oy + r)) * HW + (ox + c)] = gacc[i];
    }
}

// One MFMA conv layer LDS(in)->LDS(out). Channel-last bf16 tiles, 16B swizzle on (pix>>2)&1.
template<int SIN, int SOUT, int OSTRIDE, int OOFF, int HALO>
__device__ __forceinline__ void conv_layer_mfma(
    const unsigned short* __restrict__ inb, unsigned short* __restrict__ outb,
    const bf8* wf, f4 b4, int wave, int col, int g2, int hb,
    const int* drm, const int* dcm, int oy, int ox)
{
    constexpr int NPIX = SOUT * SOUT;
    constexpr int NT = (NPIX + 15) / 16;
    for (int t = wave; t < NT; t += 4) {
        int pp = t * 16 + col;
        int ppc = pp < NPIX ? pp : NPIX - 1;
        int r = ppc / SOUT, c = ppc - r * SOUT;
        f4 acc = b4;
        #pragma unroll
        for (int m = 0; m < 5; ++m) {
            int pin = (r + drm[m]) * SIN + (c + dcm[m]);
            const unsigned short* p = inb + pin * 16 + ((hb ^ ((pin >> 2) & 1)) << 3);
            acc = __builtin_amdgcn_mfma_f32_16x16x32_bf16(wf[m], *(const bf8*)p, acc, 0, 0, 0);
        }
        if (pp < NPIX) {
            int gy = oy + r - HALO, gx = ox + c - HALO;
            bool valid = ((unsigned)gy < (unsigned)HW) & ((unsigned)gx < (unsigned)HW);
            us4 o4;
            o4.x = f2bf(valid ? acc[0] : 0.f);
            o4.y = f2bf(valid ? acc[1] : 0.f);
            o4.z = f2bf(valid ? acc[2] : 0.f);
            o4.w = f2bf(valid ? acc[3] : 0.f);
            int pout = (r + OOFF) * OSTRIDE + (c + OOFF);
            *(us4*)(outb + pout * 16 + (((g2 >> 1) ^ ((pout >> 2) & 1)) << 3) + (g2 & 1) * 4) = o4;
        }
    }
}

// Stage B: 4 branches x 3 MFMA conv layers + fused gate accumulate
__global__ __launch_bounds__(256) void fea_mfma_kernel(
    const float* __restrict__ fea, const unsigned short* __restrict__ wa,
    const float* __restrict__ bfe, const float* __restrict__ gates,
    float* __restrict__ out)
{
    __shared__ __align__(16) unsigned short TA[22 * 22 * 16];  // 15488 B
    __shared__ __align__(16) unsigned short TB[20 * 20 * 16];  // 12800 B

    const int tid  = threadIdx.x;
    const int lane = tid & 63, wave = tid >> 6;
    const int col  = lane & 15, g2 = lane >> 4;
    const int tb   = g2 >> 1, hb = g2 & 1;
    const int b    = blockIdx.x >> 6;
    const int tile = blockIdx.x & 63;
    const int oy   = (tile >> 3) << 4;
    const int ox   = (tile & 7) << 4;

    int drm[5], dcm[5];
    #pragma unroll
    for (int m = 0; m < 5; ++m) {
        int tap = 2 * m + tb; if (tap > 8) tap = 8;
        int dr = (tap >= 6) ? 2 : ((tap >= 3) ? 1 : 0);
        drm[m] = dr; dcm[m] = tap - 3 * dr;
    }

    f4 oacc[4];
    #pragma unroll
    for (int i = 0; i < 4; ++i) oacc[i] = (f4)0.f;

    for (int g = 0; g < 4; ++g) {
        // stage features tile (halo 3) -> TA channel-last bf16, swizzled
        for (int p = tid; p < 484; p += 256) {
            int rr = p / 22, cc = p - rr * 22;
            int gy = oy - 3 + rr, gx = ox - 3 + cc;
            bool in = ((unsigned)gy < (unsigned)HW) & ((unsigned)gx < (unsigned)HW);
            #pragma unroll
            for (int h = 0; h < 2; ++h) {
                us8 uv;
                #pragma unroll
                for (int j = 0; j < 8; ++j) {
                    float v = in ? fea[(((size_t)b * 16 + h * 8 + j) * HW + gy) * HW + gx] : 0.f;
                    uv[j] = f2bf(v);
                }
                *(us8*)(TA + p * 16 + ((h ^ ((p >> 2) & 1)) << 3)) = uv;
            }
        }
        __syncthreads();

        const int gl = g * 3;
        bf8 wf[5];

        // layer 0: TA(22) -> TB(20x20)
        {
            const unsigned short* wp = wa + ((size_t)(gl + 0) * 16 + col) * 160 + g2 * 8;
            #pragma unroll
            for (int m = 0; m < 5; ++m) wf[m] = *(const bf8*)(wp + m * 32);
            f4 b4 = *(const f4*)(bfe + (gl + 0) * 16 + g2 * 4);
            conv_layer_mfma<22, 20, 20, 0, 2>(TA, TB, wf, b4, wave, col, g2, hb, drm, dcm, oy, ox);
        }
        __syncthreads();

        // layer 1: TB(20) -> TA at (2,2), 18x18
        {
            const unsigned short* wp = wa + ((size_t)(gl + 1) * 16 + col) * 160 + g2 * 8;
            #pragma unroll
            for (int m = 0; m < 5; ++m) wf[m] = *(const bf8*)(wp + m * 32);
            f4 b4 = *(const f4*)(bfe + (gl + 1) * 16 + g2 * 4);
            conv_layer_mfma<20, 18, 22, 2, 1>(TB, TA, wf, b4, wave, col, g2, hb, drm, dcm, oy, ox);
        }
        __syncthreads();

        // layer 2: TA(2,2 offset, stride 22) -> registers, fused gate accumulate
        {
            const unsigned short* wp = wa + ((size_t)(gl + 2) * 16 + col) * 160 + g2 * 8;
            #pragma unroll
            for (int m = 0; m < 5; ++m) wf[m] = *(const bf8*)(wp + m * 32);
            f4 b4 = *(const f4*)(bfe + (gl + 2) * 16 + g2 * 4);
            #pragma unroll
            for (int i = 0; i < 4; ++i) {
                int r = wave * 4 + i;
                f4 acc = b4;
                #pragma unroll
                for (int m = 0; m < 5; ++m) {
                    int pin = (r + 2 + drm[m]) * 22 + (col + 2 + dcm[m]);
                    const unsigned short* p = TA + pin * 16 + ((hb ^ ((pin >> 2) & 1)) << 3);
                    acc = __builtin_amdgcn_mfma_f32_16x16x32_bf16(wf[m], *(const bf8*)p, acc, 0, 0, 0);
                }
                float gate = gates[(((size_t)b * 4 + g) * HW + oy + r) * HW + ox + col];
                oacc[i] += gate * acc;
            }
        }
        __syncthreads();  // TA reads done before next branch restages
    }

    #pragma unroll
    for (int i = 0; i < 4; ++i) {
        int gy = oy + wave * 4 + i;
        #pragma unroll
        for (int reg = 0; reg < 4; ++reg) {
            int och = g2 * 4 + reg;
            out[(((size_t)b * 16 + och) * HW + gy) * HW + ox + col] = oacc[i][reg];
        }
    }
}

extern "C" void kernel_launch(void* const* d_in, const int* in_sizes, int n_in,
                              void* d_out, int out_size, void* d_ws, size_t ws_size,
                              hipStream_t stream) {
    const float* lm  = (const float*)d_in[0];
    const float* fea = (const float*)d_in[1];
    const float* wlm = (const float*)d_in[2];
    const float* blm = (const float*)d_in[3];
    const float* wfe = (const float*)d_in[4];
    const float* bfe = (const float*)d_in[5];
    float* out = (float*)d_out;

    float* gates = (float*)d_ws;                                  // 8 MB
    unsigned short* wa = (unsigned short*)((char*)d_ws + (size_t)NB * 4 * HW * HW * 4);

    reorder_wa_kernel<<<120, 256, 0, stream>>>(wfe, wa);
    lm_towers_kernel<<<NB * 16, 256, 0, stream>>>(lm, wlm, blm, gates);
    fea_mfma_kernel<<<NB * 64, 256, 0, stream>>>(fea, wa, bfe, gates, out);
}

// Round 3
// 435.885 us; speedup vs baseline: 3.7863x; 1.2386x over previous
//
#include <hip/hip_runtime.h>

#define HW 128
#define NB 32
#define NL 68
#define NC 16

typedef __attribute__((ext_vector_type(8))) short bf8;
typedef __attribute__((ext_vector_type(8))) unsigned short us8;
typedef __attribute__((ext_vector_type(4))) unsigned short us4;
typedef __attribute__((ext_vector_type(4))) float f4;

__device__ __forceinline__ unsigned short f2bf(float f) {
    unsigned int u = __float_as_uint(f);
    u += 0x7fffu + ((u >> 16) & 1u);   // RNE
    return (unsigned short)(u >> 16);
}

// Wa[gl][o][k]: k = m*32 + kl, kl = tp*16 + ci (tp=tap&1 within pair), tap = 2m+tp
__global__ __launch_bounds__(256) void reorder_wa_kernel(const float* __restrict__ w,
                                                         unsigned short* __restrict__ wa) {
    int i = blockIdx.x * 256 + threadIdx.x;
    if (i >= 12 * 16 * 160) return;
    int k  = i % 160;
    int o  = (i / 160) % 16;
    int gl = i / 2560;
    int kl = k & 31, m = k >> 5;
    int tap = 2 * m + (kl >> 4);
    int ci  = kl & 15;
    float v = (tap < 9) ? w[((gl * 16 + o) * 16 + ci) * 9 + tap] : 0.f;
    wa[i] = f2bf(v);
}

// Stage A: depthwise towers, split into 6 landmark chunks (one partial-gate plane each).
// chunks: 0=jaw[0,17) 1=eyeA[17,27) 2=eyeB[36,48) 3=nose[27,36) 4=mouthA[48,58) 5=mouthB[58,68)
__global__ __launch_bounds__(256) void lm_towers_kernel(
    const float* __restrict__ lm, const float* __restrict__ wlm,
    const float* __restrict__ blm, float* __restrict__ gpart)
{
    __shared__ float bufA[42 * 42];
    __shared__ float bufB[42 * 42];
    __shared__ float gacc[1024];

    const int tid   = threadIdx.x;
    const int blk   = blockIdx.x;
    const int tile  = blk & 15;
    const int chunk = (blk >> 4) % 6;
    const int b     = blk / 96;
    const int oy    = (tile >> 2) << 5;
    const int ox    = (tile & 3) << 5;

    int ls, lcnt;
    switch (chunk) {
        case 0:  ls = 0;  lcnt = 17; break;
        case 1:  ls = 17; lcnt = 10; break;
        case 2:  ls = 36; lcnt = 12; break;
        case 3:  ls = 27; lcnt = 9;  break;
        case 4:  ls = 48; lcnt = 10; break;
        default: ls = 58; lcnt = 10; break;
    }

    for (int i = tid; i < 1024; i += 256) gacc[i] = 0.f;  // slot owned by one thread

    for (int li = 0; li < lcnt; ++li) {
        const int l = ls + li;
        const float* src = lm + (size_t)(b * NL + l) * (HW * HW);
        for (int i = tid; i < 42 * 42; i += 256) {
            int r = i / 42, c = i - r * 42;
            int gy = oy - 5 + r, gx = ox - 5 + c;
            float v = 0.f;
            if ((unsigned)gy < (unsigned)HW && (unsigned)gx < (unsigned)HW)
                v = src[gy * HW + gx];
            bufA[i] = v;
        }
        __syncthreads();

        float* pin = bufA;
        float* pout = bufB;
        #pragma unroll
        for (int k = 0; k < 5; ++k) {
            const float* wp = wlm + (k * NL + l) * 9;
            float w0 = wp[0], w1 = wp[1], w2v = wp[2],
                  w3 = wp[3], w4 = wp[4], w5v = wp[5],
                  w6 = wp[6], w7 = wp[7], w8v = wp[8];
            float bias = blm[k * NL + l];
            const int lo = k + 1;
            const int HT = (40 - 2 * k) >> 1;   // compile-time after unroll
            for (int m = tid; m < HT * HT; m += 256) {
                int mr = m / HT, mc = m - mr * HT;
                int r = lo + 2 * mr, c0 = lo + 2 * mc;
                float x[4][4];
                #pragma unroll
                for (int dr = 0; dr < 4; ++dr)
                    #pragma unroll
                    for (int dc = 0; dc < 4; ++dc)
                        x[dr][dc] = pin[(r - 1 + dr) * 42 + (c0 - 1 + dc)];
                #pragma unroll
                for (int i2 = 0; i2 < 2; ++i2) {
                    #pragma unroll
                    for (int j2 = 0; j2 < 2; ++j2) {
                        float s = bias
                          + w0 * x[i2][j2]     + w1 * x[i2][j2 + 1]     + w2v * x[i2][j2 + 2]
                          + w3 * x[i2 + 1][j2] + w4 * x[i2 + 1][j2 + 1] + w5v * x[i2 + 1][j2 + 2]
                          + w6 * x[i2 + 2][j2] + w7 * x[i2 + 2][j2 + 1] + w8v * x[i2 + 2][j2 + 2];
                        int gy = oy - 5 + r + i2, gx = ox - 5 + c0 + j2;
                        bool in = (unsigned)gy < (unsigned)HW && (unsigned)gx < (unsigned)HW;
                        pout[(r + i2) * 42 + (c0 + j2)] = in ? s : 0.f;
                    }
                }
            }
            __syncthreads();
            float* t = pin; pin = pout; pout = t;
        }
        // pin = layer-5 output, valid on [5,37)^2
        for (int i = tid; i < 1024; i += 256) {
            int r = i >> 5, c = i & 31;
            gacc[i] += pin[(5 + r) * 42 + (5 + c)];
        }
        // no barrier: next iter writes bufA only, behind its own barrier
    }
    for (int i = tid; i < 1024; i += 256) {
        int r = i >> 5, c = i & 31;
        gpart[((size_t)(chunk * NB + b) * HW + (oy + r)) * HW + (ox + c)] = gacc[i];
    }
}

// Combine 6 partial planes -> 4 gate planes: eye=c1+c2, nose=c3, jaw=c0, mouth=c4+c5
__global__ __launch_bounds__(256) void combine_gates_kernel(
    const float* __restrict__ gpart, float* __restrict__ gates)
{
    const int PL = HW * HW;
    for (int i = blockIdx.x * 256 + threadIdx.x; i < NB * 4 * PL; i += gridDim.x * 256) {
        int p = i % PL;
        int g = (i / PL) & 3;
        int b = i / (PL * 4);
        float v;
        if (g == 0)      v = gpart[(size_t)(1 * NB + b) * PL + p] + gpart[(size_t)(2 * NB + b) * PL + p];
        else if (g == 1) v = gpart[(size_t)(3 * NB + b) * PL + p];
        else if (g == 2) v = gpart[(size_t)(0 * NB + b) * PL + p];
        else             v = gpart[(size_t)(4 * NB + b) * PL + p] + gpart[(size_t)(5 * NB + b) * PL + p];
        gates[i] = v;
    }
}

// One MFMA conv layer LDS(in)->LDS(out). Channel-last bf16 tiles, 16B swizzle on (pix>>2)&1.
template<int SIN, int SOUT, int OSTRIDE, int OOFF, int HALO>
__device__ __forceinline__ void conv_layer_mfma(
    const unsigned short* __restrict__ inb, unsigned short* __restrict__ outb,
    const bf8* wf, f4 b4, int wave, int col, int g2, int hb,
    const int* drm, const int* dcm, int oy, int ox)
{
    constexpr int NPIX = SOUT * SOUT;
    constexpr int NT = (NPIX + 15) / 16;
    for (int t = wave; t < NT; t += 4) {
        int pp = t * 16 + col;
        int ppc = pp < NPIX ? pp : NPIX - 1;
        int r = ppc / SOUT, c = ppc - r * SOUT;
        f4 acc = b4;
        #pragma unroll
        for (int m = 0; m < 5; ++m) {
            int pin = (r + drm[m]) * SIN + (c + dcm[m]);
            const unsigned short* p = inb + pin * 16 + ((hb ^ ((pin >> 2) & 1)) << 3);
            acc = __builtin_amdgcn_mfma_f32_16x16x32_bf16(wf[m], *(const bf8*)p, acc, 0, 0, 0);
        }
        if (pp < NPIX) {
            int gy = oy + r - HALO, gx = ox + c - HALO;
            bool valid = ((unsigned)gy < (unsigned)HW) & ((unsigned)gx < (unsigned)HW);
            us4 o4;
            o4.x = f2bf(valid ? acc[0] : 0.f);
            o4.y = f2bf(valid ? acc[1] : 0.f);
            o4.z = f2bf(valid ? acc[2] : 0.f);
            o4.w = f2bf(valid ? acc[3] : 0.f);
            int pout = (r + OOFF) * OSTRIDE + (c + OOFF);
            *(us4*)(outb + pout * 16 + (((g2 >> 1) ^ ((pout >> 2) & 1)) << 3) + (g2 & 1) * 4) = o4;
        }
    }
}

// Stage B: 4 branches x 3 MFMA conv layers + fused gate accumulate
__global__ __launch_bounds__(256) void fea_mfma_kernel(
    const float* __restrict__ fea, const unsigned short* __restrict__ wa,
    const float* __restrict__ bfe, const float* __restrict__ gates,
    float* __restrict__ out)
{
    __shared__ __align__(16) unsigned short TA[22 * 22 * 16];  // 15488 B
    __shared__ __align__(16) unsigned short TB[20 * 20 * 16];  // 12800 B

    const int tid  = threadIdx.x;
    const int lane = tid & 63, wave = tid >> 6;
    const int col  = lane & 15, g2 = lane >> 4;
    const int tb   = g2 >> 1, hb = g2 & 1;
    const int b    = blockIdx.x >> 6;
    const int tile = blockIdx.x & 63;
    const int oy   = (tile >> 3) << 4;
    const int ox   = (tile & 7) << 4;

    int drm[5], dcm[5];
    #pragma unroll
    for (int m = 0; m < 5; ++m) {
        int tap = 2 * m + tb; if (tap > 8) tap = 8;
        int dr = (tap >= 6) ? 2 : ((tap >= 3) ? 1 : 0);
        drm[m] = dr; dcm[m] = tap - 3 * dr;
    }

    f4 oacc[4];
    #pragma unroll
    for (int i = 0; i < 4; ++i) oacc[i] = (f4)0.f;

    for (int g = 0; g < 4; ++g) {
        // stage features tile (halo 3) -> TA channel-last bf16, swizzled
        for (int p = tid; p < 484; p += 256) {
            int rr = p / 22, cc = p - rr * 22;
            int gy = oy - 3 + rr, gx = ox - 3 + cc;
            bool in = ((unsigned)gy < (unsigned)HW) & ((unsigned)gx < (unsigned)HW);
            #pragma unroll
            for (int h = 0; h < 2; ++h) {
                us8 uv;
                #pragma unroll
                for (int j = 0; j < 8; ++j) {
                    float v = in ? fea[(((size_t)b * 16 + h * 8 + j) * HW + gy) * HW + gx] : 0.f;
                    uv[j] = f2bf(v);
                }
                *(us8*)(TA + p * 16 + ((h ^ ((p >> 2) & 1)) << 3)) = uv;
            }
        }
        __syncthreads();

        const int gl = g * 3;
        bf8 wf[5];

        // layer 0: TA(22) -> TB(20x20)
        {
            const unsigned short* wp = wa + ((size_t)(gl + 0) * 16 + col) * 160 + g2 * 8;
            #pragma unroll
            for (int m = 0; m < 5; ++m) wf[m] = *(const bf8*)(wp + m * 32);
            f4 b4 = *(const f4*)(bfe + (gl + 0) * 16 + g2 * 4);
            conv_layer_mfma<22, 20, 20, 0, 2>(TA, TB, wf, b4, wave, col, g2, hb, drm, dcm, oy, ox);
        }
        __syncthreads();

        // layer 1: TB(20) -> TA at (2,2), 18x18
        {
            const unsigned short* wp = wa + ((size_t)(gl + 1) * 16 + col) * 160 + g2 * 8;
            #pragma unroll
            for (int m = 0; m < 5; ++m) wf[m] = *(const bf8*)(wp + m * 32);
            f4 b4 = *(const f4*)(bfe + (gl + 1) * 16 + g2 * 4);
            conv_layer_mfma<20, 18, 22, 2, 1>(TB, TA, wf, b4, wave, col, g2, hb, drm, dcm, oy, ox);
        }
        __syncthreads();

        // layer 2: TA(2,2 offset, stride 22) -> registers, fused gate accumulate
        {
            const unsigned short* wp = wa + ((size_t)(gl + 2) * 16 + col) * 160 + g2 * 8;
            #pragma unroll
            for (int m = 0; m < 5; ++m) wf[m] = *(const bf8*)(wp + m * 32);
            f4 b4 = *(const f4*)(bfe + (gl + 2) * 16 + g2 * 4);
            #pragma unroll
            for (int i = 0; i < 4; ++i) {
                int r = wave * 4 + i;
                f4 acc = b4;
                #pragma unroll
                for (int m = 0; m < 5; ++m) {
                    int pin = (r + 2 + drm[m]) * 22 + (col + 2 + dcm[m]);
                    const unsigned short* p = TA + pin * 16 + ((hb ^ ((pin >> 2) & 1)) << 3);
                    acc = __builtin_amdgcn_mfma_f32_16x16x32_bf16(wf[m], *(const bf8*)p, acc, 0, 0, 0);
                }
                float gate = gates[(((size_t)b * 4 + g) * HW + oy + r) * HW + ox + col];
                oacc[i] += gate * acc;
            }
        }
        __syncthreads();  // TA reads done before next branch restages
    }

    #pragma unroll
    for (int i = 0; i < 4; ++i) {
        int gy = oy + wave * 4 + i;
        #pragma unroll
        for (int reg = 0; reg < 4; ++reg) {
            int och = g2 * 4 + reg;
            out[(((size_t)b * 16 + och) * HW + gy) * HW + ox + col] = oacc[i][reg];
        }
    }
}

extern "C" void kernel_launch(void* const* d_in, const int* in_sizes, int n_in,
                              void* d_out, int out_size, void* d_ws, size_t ws_size,
                              hipStream_t stream) {
    const float* lm  = (const float*)d_in[0];
    const float* fea = (const float*)d_in[1];
    const float* wlm = (const float*)d_in[2];
    const float* blm = (const float*)d_in[3];
    const float* wfe = (const float*)d_in[4];
    const float* bfe = (const float*)d_in[5];
    float* out = (float*)d_out;

    // ws layout: wa (64KB slot) | gpart 6 planes (12.6MB) | gates 4 planes (8MB)
    unsigned short* wa = (unsigned short*)d_ws;
    float* gpart = (float*)((char*)d_ws + 65536);
    float* gates = gpart + (size_t)6 * NB * HW * HW;

    reorder_wa_kernel<<<120, 256, 0, stream>>>(wfe, wa);
    lm_towers_kernel<<<NB * 16 * 6, 256, 0, stream>>>(lm, wlm, blm, gpart);
    combine_gates_kernel<<<2048, 256, 0, stream>>>(gpart, gates);
    fea_mfma_kernel<<<NB * 64, 256, 0, stream>>>(fea, wa, bfe, gates, out);
}

// Round 4
// 346.128 us; speedup vs baseline: 4.7682x; 1.2593x over previous
//
#include <hip/hip_runtime.h>

#define HW 128
#define NB 32
#define NL 68
#define NC 16

typedef __attribute__((ext_vector_type(8))) short bf8;
typedef __attribute__((ext_vector_type(8))) unsigned short us8;
typedef __attribute__((ext_vector_type(4))) unsigned short us4;
typedef __attribute__((ext_vector_type(4))) float f4;

__device__ __forceinline__ unsigned short f2bf(float f) {
    unsigned int u = __float_as_uint(f);
    u += 0x7fffu + ((u >> 16) & 1u);   // RNE
    return (unsigned short)(u >> 16);
}

// Wa[gl][o][k]: k = m*32 + kl, kl = tp*16 + ci (tp=tap&1 within pair), tap = 2m+tp
__global__ __launch_bounds__(256) void reorder_wa_kernel(const float* __restrict__ w,
                                                         unsigned short* __restrict__ wa) {
    int i = blockIdx.x * 256 + threadIdx.x;
    if (i >= 12 * 16 * 160) return;
    int k  = i % 160;
    int o  = (i / 160) % 16;
    int gl = i / 2560;
    int kl = k & 31, m = k >> 5;
    int tap = 2 * m + (kl >> 4);
    int ci  = kl & 15;
    float v = (tap < 9) ? w[((gl * 16 + o) * 16 + ci) * 9 + tap] : 0.f;
    wa[i] = f2bf(v);
}

// Stage A: depthwise towers. 8 landmark chunks, one partial-gate plane each.
// chunks: 0=[0,9) 1=[9,17) jaw | 2=[17,27) eyeA | 3=[36,42) 4=[42,48) eyeB |
//         5=[27,36) nose | 6=[48,58) 7=[58,68) mouth
// 128 threads, 32x32 tile. Layer data stored at [row][col+4], stride 52, f32.
// 4x4 micro-tile per thread, all LDS traffic via b128.
__global__ __launch_bounds__(128) void lm_towers_kernel(
    const float* __restrict__ lm, const float* __restrict__ wlm,
    const float* __restrict__ blm, float* __restrict__ gpart)
{
    __shared__ __align__(16) float bufs[2][42 * 52];   // 17472 B

    const int tid   = threadIdx.x;
    const int blk   = blockIdx.x;
    const int tile  = blk & 15;
    const int chunk = (blk >> 4) & 7;
    const int b     = blk >> 7;
    const int oy    = (tile >> 2) << 5;
    const int ox    = (tile & 3) << 5;

    int ls, lcnt;
    switch (chunk) {
        case 0:  ls = 0;  lcnt = 9;  break;
        case 1:  ls = 9;  lcnt = 8;  break;
        case 2:  ls = 17; lcnt = 10; break;
        case 3:  ls = 36; lcnt = 6;  break;
        case 4:  ls = 42; lcnt = 6;  break;
        case 5:  ls = 27; lcnt = 9;  break;
        case 6:  ls = 48; lcnt = 10; break;
        default: ls = 58; lcnt = 10; break;
    }

    float gacc[8];
    #pragma unroll
    for (int j = 0; j < 8; ++j) gacc[j] = 0.f;
    const int gr = tid >> 2;         // gate row 0..31
    const int gc = (tid & 3) << 3;   // gate col base {0,8,16,24}

    for (int li = 0; li < lcnt; ++li) {
        // accumulate previous landmark's layer-5 tile (bufs[1]) into registers
        if (li > 0) {
            const float* p5 = &bufs[1][gr * 52 + gc + 4];
            f4 a = *(const f4*)p5;
            f4 c4 = *(const f4*)(p5 + 4);
            gacc[0] += a.x; gacc[1] += a.y; gacc[2] += a.z; gacc[3] += a.w;
            gacc[4] += c4.x; gacc[5] += c4.y; gacc[6] += c4.z; gacc[7] += c4.w;
        }
        // stage landmark input (42x42 halo tile) into bufs[0]
        const int l = ls + li;
        const float* src = lm + (size_t)(b * NL + l) * (HW * HW);
        for (int i = tid; i < 42 * 42; i += 128) {
            int r = i / 42, c = i - r * 42;
            int gy = oy - 5 + r, gx = ox - 5 + c;
            float v = 0.f;
            if ((unsigned)gy < (unsigned)HW && (unsigned)gx < (unsigned)HW)
                v = src[gy * HW + gx];
            bufs[0][r * 52 + c + 4] = v;
        }
        __syncthreads();

        #pragma unroll
        for (int k = 0; k < 5; ++k) {
            const float* wp = wlm + (k * NL + l) * 9;
            float wv[3][3];
            #pragma unroll
            for (int t = 0; t < 9; ++t) wv[t / 3][t % 3] = wp[t];
            float bias = blm[k * NL + l];
            const int G = (43 - 2 * k) >> 2;    // 10,10,9,9,8 (compile-time)
            const float* pin = bufs[k & 1];
            float* pout = bufs[(k + 1) & 1];
            if (tid < G * G) {
                int mr = tid / G, mc = tid - mr * G;
                int r0 = mr << 2, c0 = mc << 2;
                float o[4][4];
                #pragma unroll
                for (int i = 0; i < 4; ++i)
                    #pragma unroll
                    for (int j = 0; j < 4; ++j) o[i][j] = bias;
                #pragma unroll
                for (int rr = 0; rr < 6; ++rr) {
                    const float* prow = pin + (r0 + rr) * 52 + c0 + 4;
                    f4 xa = *(const f4*)prow;
                    f4 xb = *(const f4*)(prow + 4);
                    float x0 = xa.x, x1 = xa.y, x2 = xa.z, x3 = xa.w, x4 = xb.x, x5 = xb.y;
                    #pragma unroll
                    for (int orow = 0; orow < 4; ++orow) {
                        const int dr = rr - orow;
                        if (dr < 0 || dr > 2) continue;
                        o[orow][0] += wv[dr][0] * x0 + wv[dr][1] * x1 + wv[dr][2] * x2;
                        o[orow][1] += wv[dr][0] * x1 + wv[dr][1] * x2 + wv[dr][2] * x3;
                        o[orow][2] += wv[dr][0] * x2 + wv[dr][1] * x3 + wv[dr][2] * x4;
                        o[orow][3] += wv[dr][0] * x3 + wv[dr][1] * x4 + wv[dr][2] * x5;
                    }
                }
                // image-boundary mask (outside-image intermediates must be 0) + b128 store
                #pragma unroll
                for (int i = 0; i < 4; ++i) {
                    int gy = oy + r0 + i + k - 4;
                    bool vy = (unsigned)gy < (unsigned)HW;
                    f4 st;
                    {
                        bool v0 = vy && (unsigned)(ox + c0 + 0 + k - 4) < (unsigned)HW;
                        bool v1 = vy && (unsigned)(ox + c0 + 1 + k - 4) < (unsigned)HW;
                        bool v2 = vy && (unsigned)(ox + c0 + 2 + k - 4) < (unsigned)HW;
                        bool v3 = vy && (unsigned)(ox + c0 + 3 + k - 4) < (unsigned)HW;
                        st.x = v0 ? o[i][0] : 0.f;
                        st.y = v1 ? o[i][1] : 0.f;
                        st.z = v2 ? o[i][2] : 0.f;
                        st.w = v3 ? o[i][3] : 0.f;
                    }
                    *(f4*)(pout + (r0 + i) * 52 + c0 + 4) = st;
                }
            }
            __syncthreads();
        }
    }
    // final landmark's layer-5 tile
    {
        const float* p5 = &bufs[1][gr * 52 + gc + 4];
        f4 a = *(const f4*)p5;
        f4 c4 = *(const f4*)(p5 + 4);
        gacc[0] += a.x; gacc[1] += a.y; gacc[2] += a.z; gacc[3] += a.w;
        gacc[4] += c4.x; gacc[5] += c4.y; gacc[6] += c4.z; gacc[7] += c4.w;
    }
    float* gp = gpart + ((size_t)(chunk * NB + b) * HW + (oy + gr)) * HW + ox + gc;
    f4 s0 = {gacc[0], gacc[1], gacc[2], gacc[3]};
    f4 s1 = {gacc[4], gacc[5], gacc[6], gacc[7]};
    *(f4*)gp = s0;
    *(f4*)(gp + 4) = s1;
}

// One MFMA conv layer LDS(in)->LDS(out). Channel-last bf16 tiles, 16B swizzle on (pix>>2)&1.
template<int SIN, int SOUT, int OSTRIDE, int OOFF, int HALO>
__device__ __forceinline__ void conv_layer_mfma(
    const unsigned short* __restrict__ inb, unsigned short* __restrict__ outb,
    const bf8* wf, f4 b4, int wave, int col, int g2, int hb,
    const int* drm, const int* dcm, int oy, int ox)
{
    constexpr int NPIX = SOUT * SOUT;
    constexpr int NT = (NPIX + 15) / 16;
    for (int t = wave; t < NT; t += 4) {
        int pp = t * 16 + col;
        int ppc = pp < NPIX ? pp : NPIX - 1;
        int r = ppc / SOUT, c = ppc - r * SOUT;
        f4 acc = b4;
        #pragma unroll
        for (int m = 0; m < 5; ++m) {
            int pin = (r + drm[m]) * SIN + (c + dcm[m]);
            const unsigned short* p = inb + pin * 16 + ((hb ^ ((pin >> 2) & 1)) << 3);
            acc = __builtin_amdgcn_mfma_f32_16x16x32_bf16(wf[m], *(const bf8*)p, acc, 0, 0, 0);
        }
        if (pp < NPIX) {
            int gy = oy + r - HALO, gx = ox + c - HALO;
            bool valid = ((unsigned)gy < (unsigned)HW) & ((unsigned)gx < (unsigned)HW);
            us4 o4;
            o4.x = f2bf(valid ? acc[0] : 0.f);
            o4.y = f2bf(valid ? acc[1] : 0.f);
            o4.z = f2bf(valid ? acc[2] : 0.f);
            o4.w = f2bf(valid ? acc[3] : 0.f);
            int pout = (r + OOFF) * OSTRIDE + (c + OOFF);
            *(us4*)(outb + pout * 16 + (((g2 >> 1) ^ ((pout >> 2) & 1)) << 3) + (g2 & 1) * 4) = o4;
        }
    }
}

// Stage B: 4 branches x 3 MFMA conv layers + fused gate accumulate (reads gpart directly)
__global__ __launch_bounds__(256) void fea_mfma_kernel(
    const float* __restrict__ fea, const unsigned short* __restrict__ wa,
    const float* __restrict__ bfe, const float* __restrict__ gpart,
    float* __restrict__ out)
{
    __shared__ __align__(16) unsigned short TA[22 * 22 * 16];  // 15488 B
    __shared__ __align__(16) unsigned short TB[20 * 20 * 16];  // 12800 B

    const int tid  = threadIdx.x;
    const int lane = tid & 63, wave = tid >> 6;
    const int col  = lane & 15, g2 = lane >> 4;
    const int tb   = g2 >> 1, hb = g2 & 1;
    const int b    = blockIdx.x >> 6;
    const int tile = blockIdx.x & 63;
    const int oy   = (tile >> 3) << 4;
    const int ox   = (tile & 7) << 4;

    int drm[5], dcm[5];
    #pragma unroll
    for (int m = 0; m < 5; ++m) {
        int tap = 2 * m + tb; if (tap > 8) tap = 8;
        int dr = (tap >= 6) ? 2 : ((tap >= 3) ? 1 : 0);
        drm[m] = dr; dcm[m] = tap - 3 * dr;
    }

    f4 oacc[4];
    #pragma unroll
    for (int i = 0; i < 4; ++i) oacc[i] = (f4)0.f;

    for (int g = 0; g < 4; ++g) {
        // stage features tile (halo 3) -> TA channel-last bf16, swizzled
        for (int p = tid; p < 484; p += 256) {
            int rr = p / 22, cc = p - rr * 22;
            int gy = oy - 3 + rr, gx = ox - 3 + cc;
            bool in = ((unsigned)gy < (unsigned)HW) & ((unsigned)gx < (unsigned)HW);
            #pragma unroll
            for (int h = 0; h < 2; ++h) {
                us8 uv;
                #pragma unroll
                for (int j = 0; j < 8; ++j) {
                    float v = in ? fea[(((size_t)b * 16 + h * 8 + j) * HW + gy) * HW + gx] : 0.f;
                    uv[j] = f2bf(v);
                }
                *(us8*)(TA + p * 16 + ((h ^ ((p >> 2) & 1)) << 3)) = uv;
            }
        }
        __syncthreads();

        const int gl = g * 3;
        bf8 wf[5];

        // layer 0: TA(22) -> TB(20x20)
        {
            const unsigned short* wp = wa + ((size_t)(gl + 0) * 16 + col) * 160 + g2 * 8;
            #pragma unroll
            for (int m = 0; m < 5; ++m) wf[m] = *(const bf8*)(wp + m * 32);
            f4 b4 = *(const f4*)(bfe + (gl + 0) * 16 + g2 * 4);
            conv_layer_mfma<22, 20, 20, 0, 2>(TA, TB, wf, b4, wave, col, g2, hb, drm, dcm, oy, ox);
        }
        __syncthreads();

        // layer 1: TB(20) -> TA at (2,2), 18x18
        {
            const unsigned short* wp = wa + ((size_t)(gl + 1) * 16 + col) * 160 + g2 * 8;
            #pragma unroll
            for (int m = 0; m < 5; ++m) wf[m] = *(const bf8*)(wp + m * 32);
            f4 b4 = *(const f4*)(bfe + (gl + 1) * 16 + g2 * 4);
            conv_layer_mfma<20, 18, 22, 2, 1>(TB, TA, wf, b4, wave, col, g2, hb, drm, dcm, oy, ox);
        }
        __syncthreads();

        // layer 2: TA(2,2 offset, stride 22) -> registers, fused gate accumulate
        {
            const unsigned short* wp = wa + ((size_t)(gl + 2) * 16 + col) * 160 + g2 * 8;
            #pragma unroll
            for (int m = 0; m < 5; ++m) wf[m] = *(const bf8*)(wp + m * 32);
            f4 b4 = *(const f4*)(bfe + (gl + 2) * 16 + g2 * 4);
            // partial-plane list for this gate: eye=2,3,4  nose=5  jaw=0,1  mouth=6,7
            int p0, np;
            if (g == 0)      { p0 = 2; np = 3; }
            else if (g == 1) { p0 = 5; np = 1; }
            else if (g == 2) { p0 = 0; np = 2; }
            else             { p0 = 6; np = 2; }
            #pragma unroll
            for (int i = 0; i < 4; ++i) {
                int r = wave * 4 + i;
                f4 acc = b4;
                #pragma unroll
                for (int m = 0; m < 5; ++m) {
                    int pin = (r + 2 + drm[m]) * 22 + (col + 2 + dcm[m]);
                    const unsigned short* p = TA + pin * 16 + ((hb ^ ((pin >> 2) & 1)) << 3);
                    acc = __builtin_amdgcn_mfma_f32_16x16x32_bf16(wf[m], *(const bf8*)p, acc, 0, 0, 0);
                }
                float gate = 0.f;
                for (int pp = 0; pp < np; ++pp)
                    gate += gpart[(size_t)((p0 + pp) * NB + b) * (HW * HW)
                                  + (size_t)(oy + r) * HW + ox + col];
                oacc[i] += gate * acc;
            }
        }
        __syncthreads();  // TA reads done before next branch restages
    }

    #pragma unroll
    for (int i = 0; i < 4; ++i) {
        int gy = oy + wave * 4 + i;
        #pragma unroll
        for (int reg = 0; reg < 4; ++reg) {
            int och = g2 * 4 + reg;
            out[(((size_t)b * 16 + och) * HW + gy) * HW + ox + col] = oacc[i][reg];
        }
    }
}

extern "C" void kernel_launch(void* const* d_in, const int* in_sizes, int n_in,
                              void* d_out, int out_size, void* d_ws, size_t ws_size,
                              hipStream_t stream) {
    const float* lm  = (const float*)d_in[0];
    const float* fea = (const float*)d_in[1];
    const float* wlm = (const float*)d_in[2];
    const float* blm = (const float*)d_in[3];
    const float* wfe = (const float*)d_in[4];
    const float* bfe = (const float*)d_in[5];
    float* out = (float*)d_out;

    // ws layout: wa (64KB slot) | gpart 8 partial planes (16.8MB)
    unsigned short* wa = (unsigned short*)d_ws;
    float* gpart = (float*)((char*)d_ws + 65536);

    reorder_wa_kernel<<<120, 256, 0, stream>>>(wfe, wa);
    lm_towers_kernel<<<NB * 16 * 8, 128, 0, stream>>>(lm, wlm, blm, gpart);
    fea_mfma_kernel<<<NB * 64, 256, 0, stream>>>(fea, wa, bfe, gpart, out);
}